// Round 7
// baseline (321.361 us; speedup 1.0000x reference)
//
#include <hip/hip_runtime.h>
#include <hip/hip_bf16.h>

#define HW_N 2304
#define EPS_F 1e-5f
#define QSCALE 0.18033688011112043f   // 0.125 * log2(e)

typedef float f32x4 __attribute__((ext_vector_type(4)));
typedef float f32x16 __attribute__((ext_vector_type(16)));
typedef unsigned u32x4 __attribute__((ext_vector_type(4)));
typedef short short8v __attribute__((ext_vector_type(8)));
typedef __bf16 bf16x8 __attribute__((ext_vector_type(8)));
typedef unsigned short u16;

__device__ __forceinline__ f32x4 mfma_bf16(bf16x8 a, bf16x8 b, f32x4 c) {
    return __builtin_amdgcn_mfma_f32_16x16x32_bf16(a, b, c, 0, 0, 0);
}
__device__ __forceinline__ f32x16 mfma32(bf16x8 a, bf16x8 b, f32x16 c) {
    return __builtin_amdgcn_mfma_f32_32x32x16_bf16(a, b, c, 0, 0, 0);
}
__device__ __forceinline__ bf16x8 ld8(const void* p) {
    return __builtin_bit_cast(bf16x8, *(const short8v*)p);
}
__device__ __forceinline__ unsigned short bfbits(float v) {
    return __builtin_bit_cast(unsigned short, __float2bfloat16(v));
}
__device__ __forceinline__ float b2f(u16 u) {
    unsigned x = (unsigned)u << 16;
    return __builtin_bit_cast(float, x);
}
__device__ __forceinline__ unsigned pack2(float lo, float hi) {
    return (unsigned)bfbits(lo) | ((unsigned)bfbits(hi) << 16);
}
__device__ __forceinline__ f32x16 zero16() {
    f32x16 z;
#pragma unroll
    for (int i = 0; i < 16; ++i) z[i] = 0.f;
    return z;
}

// ---------------------------------------------------------------------------
// Prep: convert 9 weight matrices fp32 -> bf16
// ---------------------------------------------------------------------------
struct WPtrs { const float* s[9]; u16* d[9]; };

__global__ __launch_bounds__(256)
void conv_w_kernel(WPtrs p)
{
    const int j = blockIdx.z;
    const float* s = p.s[j];
    u16* d = p.d[j];
    const int i = (blockIdx.x * 256 + threadIdx.x) * 4;
    const float4 v = *(const float4*)(s + i);
    ushort4 pk;
    pk.x = bfbits(v.x); pk.y = bfbits(v.y); pk.z = bfbits(v.z); pk.w = bfbits(v.w);
    *(ushort4*)(d + i) = pk;
}

// ---------------------------------------------------------------------------
// Prep: transpose modal feats [b][256][2304] fp32 -> [b][2304][256] bf16
// ---------------------------------------------------------------------------
__global__ __launch_bounds__(256)
void prep_modal_kernel(const float* __restrict__ m1, const float* __restrict__ m2,
                       u16* __restrict__ t1, u16* __restrict__ t2)
{
    const int l0 = blockIdx.x * 64, c0 = blockIdx.y * 64;
    const int which = blockIdx.z >> 1, b = blockIdx.z & 1;
    const float* src = (which ? m2 : m1) + ((long long)b * 256 + c0) * HW_N + l0;
    u16* dst = (which ? t2 : t1) + ((long long)b * HW_N + l0) * 256 + c0;

    __shared__ float tile[64][65];
    const int t = threadIdx.x;
    const int r = t >> 4, cq = (t & 15) * 4;
#pragma unroll
    for (int i = 0; i < 4; ++i) {
        const int row = r + i * 16;
        const float4 v = *(const float4*)(src + (long long)row * HW_N + cq);
        tile[row][cq + 0] = v.x; tile[row][cq + 1] = v.y;
        tile[row][cq + 2] = v.z; tile[row][cq + 3] = v.w;
    }
    __syncthreads();
#pragma unroll
    for (int i = 0; i < 4; ++i) {
        const int lr = r + i * 16;
        ushort4 pk;
        pk.x = bfbits(tile[cq + 0][lr]);
        pk.y = bfbits(tile[cq + 1][lr]);
        pk.z = bfbits(tile[cq + 2][lr]);
        pk.w = bfbits(tile[cq + 3][lr]);
        *(ushort4*)(dst + (long long)lr * 256 + cq) = pk;
    }
}

// ---------------------------------------------------------------------------
// Generic MFMA GEMM (unchanged)
// ---------------------------------------------------------------------------
struct GArgs {
    const u16* W[6];
    const float* bias[6];
    const u16* X[2];
    const u16* R[2];
    u16* outQ[2]; u16* outK[2]; u16* outV[2];
    float* outT[2];
    float* outC;
    const float *bnm, *bnv, *bng, *bnb;
};

template<int MODE>
__global__ __launch_bounds__(256)
void gemm_mfma(GArgs g)
{
    constexpr int KD = (MODE == 0) ? 256 : 512;
    constexpr int NS = KD / 32;
    const int z = blockIdx.y;
    const int j = blockIdx.z;
    const int mt_b = blockIdx.x / 18;
    const int nt_b = blockIdx.x - mt_b * 18;
    const int m0 = mt_b * 128, n0 = nt_b * 128;

    const u16* Wb = g.W[(MODE == 2) ? 0 : j];
    const u16* Xb0 = (MODE == 0) ? g.X[(j < 3) ? 0 : 1]
                                 : ((MODE == 1) ? g.X[j] : nullptr);

    __shared__ u16 Als[4096];
    __shared__ u16 Bls[4096];

    const int tid = threadIdx.x;
    const int w = tid >> 6, lane = tid & 63;
    const int l16 = lane & 15, lg = lane >> 4;

    const int ar0 = (((tid >> 6) << 4) | (tid & 15));
    const int k8 = (tid >> 4) & 3;

    short8v sa0, sa1, sb0, sb1;

    auto stage = [&](int kb) {
        const int koff = kb + k8 * 8;
        sa0 = *(const short8v*)(Wb + (long long)(m0 + ar0) * KD + koff);
        sa1 = *(const short8v*)(Wb + (long long)(m0 + ar0 + 64) * KD + koff);
        if constexpr (MODE == 0) {
            const u16* p = Xb0 + ((long long)z * HW_N + n0 + ar0) * 256 + koff;
            sb0 = *(const short8v*)p;
            sb1 = *(const short8v*)(p + 64LL * 256);
        } else if constexpr (MODE == 1) {
            const int head = kb >> 6;
            const u16* p = Xb0 + (((long long)z * 8 + head) * HW_N + n0 + ar0) * 64 + (koff & 63);
            sb0 = *(const short8v*)p;
            sb1 = *(const short8v*)(p + 64LL * 64);
        } else {
            const u16* Xb = (kb < 256) ? g.X[0] : g.X[1];
            const u16* p = Xb + ((long long)z * HW_N + n0 + ar0) * 256 + (koff & 255);
            sb0 = *(const short8v*)p;
            sb1 = *(const short8v*)(p + 64LL * 256);
        }
    };

    f32x4 acc[4][4];
#pragma unroll
    for (int a = 0; a < 4; ++a)
#pragma unroll
        for (int b = 0; b < 4; ++b) acc[a][b] = f32x4{0.f, 0.f, 0.f, 0.f};

    stage(0);
    for (int s = 0; s < NS; ++s) {
        __syncthreads();
        *(short8v*)((char*)Als + tid * 16) = sa0;
        *(short8v*)((char*)Als + tid * 16 + 4096) = sa1;
        *(short8v*)((char*)Bls + tid * 16) = sb0;
        *(short8v*)((char*)Bls + tid * 16 + 4096) = sb1;
        __syncthreads();
        if (s + 1 < NS) stage((s + 1) * 32);

        bf16x8 bfr[4];
#pragma unroll
        for (int nt = 0; nt < 4; ++nt)
            bfr[nt] = ld8((char*)Bls + ((w & 1) * 4 + nt) * 1024 + lane * 16);
#pragma unroll
        for (int mt = 0; mt < 4; ++mt) {
            const bf16x8 af = ld8((char*)Als + ((w >> 1) * 4 + mt) * 1024 + lane * 16);
#pragma unroll
            for (int nt = 0; nt < 4; ++nt)
                acc[mt][nt] = mfma_bf16(af, bfr[nt], acc[mt][nt]);
        }
    }

    const int mbase = m0 + (w >> 1) * 64 + 4 * lg;
    const int nbase = n0 + (w & 1) * 64 + l16;

    if constexpr (MODE == 0) {
        const int kind = j % 3, which = j / 3;
        const float* Bp = g.bias[j];
        if (kind < 2) {
            u16* T = (kind == 0) ? g.outQ[which] : g.outK[which];
            const float s = (kind == 0) ? QSCALE : 1.0f;
#pragma unroll
            for (int mt = 0; mt < 4; ++mt) {
                const int m = mbase + mt * 16;
                const float4 bv = *(const float4*)(Bp + m);
#pragma unroll
                for (int nt = 0; nt < 4; ++nt) {
                    const int l = nbase + nt * 16;
                    const f32x4 a = acc[mt][nt];
                    ushort4 pk;
                    pk.x = bfbits((a.x + bv.x) * s);
                    pk.y = bfbits((a.y + bv.y) * s);
                    pk.z = bfbits((a.z + bv.z) * s);
                    pk.w = bfbits((a.w + bv.w) * s);
                    *(ushort4*)(T + ((long long)(z * 8 + (m >> 6)) * HW_N + l) * 64 + (m & 63)) = pk;
                }
            }
        } else {
            u16* V = g.outV[which];
#pragma unroll
            for (int mt = 0; mt < 4; ++mt) {
                const int m = mbase + mt * 16;
                const float4 bv = *(const float4*)(Bp + m);
#pragma unroll
                for (int nt = 0; nt < 4; ++nt) {
                    const int l = nbase + nt * 16;
                    const f32x4 a = acc[mt][nt];
                    V[((long long)z * 512 + m + 0) * HW_N + l] = bfbits(a.x + bv.x);
                    V[((long long)z * 512 + m + 1) * HW_N + l] = bfbits(a.y + bv.y);
                    V[((long long)z * 512 + m + 2) * HW_N + l] = bfbits(a.z + bv.z);
                    V[((long long)z * 512 + m + 3) * HW_N + l] = bfbits(a.w + bv.w);
                }
            }
        }
    } else if constexpr (MODE == 1) {
        const float* Bp = g.bias[j];
        const u16* Rb = g.R[j];
        float* Ob = g.outT[j];
#pragma unroll
        for (int mt = 0; mt < 4; ++mt) {
            const int m = mbase + mt * 16;
            const float4 bv = *(const float4*)(Bp + m);
#pragma unroll
            for (int nt = 0; nt < 4; ++nt) {
                const int l = nbase + nt * 16;
                const long long rowoff = ((long long)z * HW_N + l) * 256 + m;
                const ushort4 rv = *(const ushort4*)(Rb + rowoff);
                const f32x4 a = acc[mt][nt];
                float4 o;
                o.x = a.x + bv.x + b2f(rv.x);
                o.y = a.y + bv.y + b2f(rv.y);
                o.z = a.z + bv.z + b2f(rv.z);
                o.w = a.w + bv.w + b2f(rv.w);
                *(float4*)(Ob + rowoff) = o;
            }
        }
    } else {
        const float* Bp = g.bias[0];
#pragma unroll
        for (int mt = 0; mt < 4; ++mt) {
            const int m = mbase + mt * 16;
            const float4 bv = *(const float4*)(Bp + m);
            const float4 mu = *(const float4*)(g.bnm + m);
            const float4 vr = *(const float4*)(g.bnv + m);
            const float4 ga = *(const float4*)(g.bng + m);
            const float4 be = *(const float4*)(g.bnb + m);
            const float sc0 = ga.x * rsqrtf(vr.x + EPS_F), sh0 = be.x - mu.x * sc0;
            const float sc1 = ga.y * rsqrtf(vr.y + EPS_F), sh1 = be.y - mu.y * sc1;
            const float sc2 = ga.z * rsqrtf(vr.z + EPS_F), sh2 = be.z - mu.z * sc2;
            const float sc3 = ga.w * rsqrtf(vr.w + EPS_F), sh3 = be.w - mu.w * sc3;
#pragma unroll
            for (int nt = 0; nt < 4; ++nt) {
                const int l = nbase + nt * 16;
                const f32x4 a = acc[mt][nt];
                float* O = g.outC + (long long)z * 256 * HW_N + l;
                O[(long long)(m + 0) * HW_N] = fmaxf((a.x + bv.x) * sc0 + sh0, 0.f);
                O[(long long)(m + 1) * HW_N] = fmaxf((a.y + bv.y) * sc1 + sh1, 0.f);
                O[(long long)(m + 2) * HW_N] = fmaxf((a.z + bv.z) * sc2 + sh2, 0.f);
                O[(long long)(m + 3) * HW_N] = fmaxf((a.w + bv.w) * sc3 + sh3, 0.f);
            }
        }
    }
}

// ---------------------------------------------------------------------------
// MFMA flash cross-attention v5: split-KV x2 (flash-decoding).
// 1152 blocks, each does 18 of 36 kv-tiles, emits unnormalized partials
// (PO f32[64], PM=m, PS=s). Body identical to v4 otherwise.
// ---------------------------------------------------------------------------
__global__ __launch_bounds__(256, 4)
void attn_mfma_kernel(const u16* __restrict__ qt0, const u16* __restrict__ kt0,
                      const u16* __restrict__ v0b,
                      const u16* __restrict__ qt1, const u16* __restrict__ kt1,
                      const u16* __restrict__ v1b,
                      float* __restrict__ PO, float* __restrict__ PM,
                      float* __restrict__ PS)
{
    // XCD swizzle over 1152 blocks: each XCD gets one (split,b,dir) x 8h x 18lt
    const int flat = blockIdx.x;
    const int virt = (flat & 7) * 144 + (flat >> 3);
    const int lt = virt % 18;
    const int rest = virt / 18;          // [0,64)
    const int h = rest & 7;
    const int zz2 = rest >> 3;           // [0,8)
    const int zz = zz2 & 3;
    const int sp = zz2 >> 2;             // kv split
    const int b = zz >> 1, dir = zz & 1;
    const int t0 = sp * 18;

    const u16* QT = dir ? qt1 : qt0;
    const u16* KT = dir ? kt0 : kt1;
    const u16* V  = dir ? v0b : v1b;

    const long long bh = (long long)(b * 8 + h);
    const u16* Qb = QT + bh * HW_N * 64;
    const u16* Kb = KT + bh * HW_N * 64;
    const u16* Vb = V + ((long long)b * 512 + h * 64) * HW_N;

    const int tid = threadIdx.x;
    const int w = tid >> 6, lane = tid & 63;
    const int l32 = lane & 31, hi = lane >> 5;
    const int q0 = lt * 128 + w * 32;

    __shared__ u16 Ks[2][64 * 64];
    __shared__ u16 Vs[2][64 * 64];

    bf16x8 qf0, qf1, qf2, qf3;
    {
        const u16* qrow = Qb + (long long)(q0 + l32) * 64 + 8 * hi;
        qf0 = ld8(qrow);       qf1 = ld8(qrow + 16);
        qf2 = ld8(qrow + 32);  qf3 = ld8(qrow + 48);
    }
    bf16x8 onesv;
    {
        short8v o;
#pragma unroll
        for (int i = 0; i < 8; ++i) o[i] = (short)0x3F80;
        onesv = __builtin_bit_cast(bf16x8, o);
    }

    f32x16 accA = zero16(), accB = zero16(), accs = zero16();
    float m_run = -1e30f;

    auto SWZ = [](int r) { return ((r ^ (r >> 3)) & 7) << 4; };

    const int rsub = lane >> 3;
    const int csub = (lane & 7) * 8;
    const int r0 = 16 * w + rsub, r1 = r0 + 8;
    const int swz0 = (csub * 2) ^ SWZ(r0);
    const int swz1 = (csub * 2) ^ SWZ(r1);

    short8v ka, kb2, va, vb2;
    auto stage = [&](int t) {          // t = global kv-tile index
        const int m0 = t * 64;
        const u16* kbase = Kb + (long long)(m0 + 16 * w) * 64;
        ka  = *(const short8v*)(kbase + (long long)rsub * 64 + csub);
        kb2 = *(const short8v*)(kbase + (long long)(8 + rsub) * 64 + csub);
        const u16* vbase = Vb + (long long)(16 * w + rsub) * HW_N + m0 + csub;
        va  = *(const short8v*)(vbase);
        vb2 = *(const short8v*)(vbase + 8LL * HW_N);
    };
    auto commit = [&](int buf) {
        *(short8v*)((char*)Ks[buf] + r0 * 128 + swz0) = ka;
        *(short8v*)((char*)Ks[buf] + r1 * 128 + swz1) = kb2;
        *(short8v*)((char*)Vs[buf] + r0 * 128 + swz0) = va;
        *(short8v*)((char*)Vs[buf] + r1 * 128 + swz1) = vb2;
    };

    const int rb0 = l32 * 128;
    const int rb1 = (l32 + 32) * 128;
    const int cs0 = (16 * hi) ^ SWZ(l32);
    const int cs1 = (16 * hi) ^ SWZ(l32 + 32);

    stage(t0); commit(0); stage(t0 + 1);
    __syncthreads();

    for (int t = 0; t < 18; ++t) {
        const int cur = t & 1;
        const char* kbase = (const char*)Ks[cur];
        const char* vbase = (const char*)Vs[cur];

        const bf16x8 kf00 = ld8(kbase + rb0 + (cs0 ^ 0));
        const bf16x8 kf01 = ld8(kbase + rb1 + (cs1 ^ 0));
        const bf16x8 kf10 = ld8(kbase + rb0 + (cs0 ^ 32));
        const bf16x8 kf11 = ld8(kbase + rb1 + (cs1 ^ 32));
        const bf16x8 kf20 = ld8(kbase + rb0 + (cs0 ^ 64));
        const bf16x8 kf21 = ld8(kbase + rb1 + (cs1 ^ 64));
        const bf16x8 kf30 = ld8(kbase + rb0 + (cs0 ^ 96));
        const bf16x8 kf31 = ld8(kbase + rb1 + (cs1 ^ 96));

        if (t + 1 < 18) commit(cur ^ 1);
        if (t + 2 < 18) stage(t0 + t + 2);

        f32x16 s0 = zero16(), s1 = zero16();
        __builtin_amdgcn_s_setprio(1);
        s0 = mfma32(kf00, qf0, s0); s1 = mfma32(kf01, qf0, s1);
        s0 = mfma32(kf10, qf1, s0); s1 = mfma32(kf11, qf1, s1);
        s0 = mfma32(kf20, qf2, s0); s1 = mfma32(kf21, qf2, s1);
        s0 = mfma32(kf30, qf3, s0); s1 = mfma32(kf31, qf3, s1);
        __builtin_amdgcn_s_setprio(0);

        const bf16x8 vf00 = ld8(vbase + rb0 + (cs0 ^ 0));
        const bf16x8 vf01 = ld8(vbase + rb1 + (cs1 ^ 0));
        const bf16x8 vf10 = ld8(vbase + rb0 + (cs0 ^ 32));
        const bf16x8 vf11 = ld8(vbase + rb1 + (cs1 ^ 32));
        const bf16x8 vf20 = ld8(vbase + rb0 + (cs0 ^ 64));
        const bf16x8 vf21 = ld8(vbase + rb1 + (cs1 ^ 64));
        const bf16x8 vf30 = ld8(vbase + rb0 + (cs0 ^ 96));
        const bf16x8 vf31 = ld8(vbase + rb1 + (cs1 ^ 96));

        f32x16 mv;
#pragma unroll
        for (int i = 0; i < 16; ++i) mv[i] = fmaxf(s0[i], s1[i]);
        float ma = fmaxf(fmaxf(mv[0], mv[1]), fmaxf(mv[2], mv[3]));
        float mb = fmaxf(fmaxf(mv[4], mv[5]), fmaxf(mv[6], mv[7]));
        float mc = fmaxf(fmaxf(mv[8], mv[9]), fmaxf(mv[10], mv[11]));
        float md = fmaxf(fmaxf(mv[12], mv[13]), fmaxf(mv[14], mv[15]));
        float mx = fmaxf(fmaxf(ma, mb), fmaxf(mc, md));
        {
            unsigned mu = __builtin_bit_cast(unsigned, mx);
            unsigned mv2 = mu;
            asm("v_permlane32_swap_b32 %0, %1" : "+v"(mu), "+v"(mv2));
            mx = fmaxf(__builtin_bit_cast(float, mu), __builtin_bit_cast(float, mv2));
        }

        if (!__all(mx <= m_run + 8.f)) {
            const float m_new = fmaxf(m_run, mx);
            const float alpha = exp2f(m_run - m_new);
#pragma unroll
            for (int i = 0; i < 16; ++i) {
                accA[i] *= alpha; accB[i] *= alpha; accs[i] *= alpha;
            }
            m_run = m_new;
        }

#pragma unroll
        for (int i = 0; i < 16; ++i) {
            s0[i] = exp2f(s0[i] - m_run);
            s1[i] = exp2f(s1[i] - m_run);
        }

        __builtin_amdgcn_s_setprio(1);
#define PVSTEP(S, PT, VF0, VF1) { \
        constexpr int qe = 2 * ((S) & 1), qo = qe + 1; \
        unsigned a0 = pack2(PT[4 * qe + 0], PT[4 * qe + 1]); \
        unsigned b0 = pack2(PT[4 * qe + 2], PT[4 * qe + 3]); \
        unsigned a1 = pack2(PT[4 * qo + 0], PT[4 * qo + 1]); \
        unsigned b1 = pack2(PT[4 * qo + 2], PT[4 * qo + 3]); \
        asm("v_permlane32_swap_b32 %0, %1" : "+v"(a0), "+v"(a1)); \
        asm("v_permlane32_swap_b32 %0, %1" : "+v"(b0), "+v"(b1)); \
        u32x4 pw = {a0, b0, a1, b1}; \
        const bf16x8 pf = __builtin_bit_cast(bf16x8, pw); \
        accA = mfma32(VF0, pf, accA); \
        accB = mfma32(VF1, pf, accB); \
        accs = mfma32(onesv, pf, accs); }
        PVSTEP(0, s0, vf00, vf01)
        PVSTEP(1, s0, vf10, vf11)
        PVSTEP(2, s1, vf20, vf21)
        PVSTEP(3, s1, vf30, vf31)
#undef PVSTEP
        __builtin_amdgcn_s_setprio(0);

        __syncthreads();
    }

    // ---- partial epilogue: unnormalized O (f32), m, s
    const long long prow = ((long long)sp * 32 + (zz * 8 + h)) * HW_N + q0 + l32;
    float* POr = PO + prow * 64;
#pragma unroll
    for (int g = 0; g < 4; ++g) {
        float4 o;
        o.x = accA[4 * g + 0]; o.y = accA[4 * g + 1];
        o.z = accA[4 * g + 2]; o.w = accA[4 * g + 3];
        *(float4*)(POr + 8 * g + 4 * hi) = o;
        o.x = accB[4 * g + 0]; o.y = accB[4 * g + 1];
        o.z = accB[4 * g + 2]; o.w = accB[4 * g + 3];
        *(float4*)(POr + 32 + 8 * g + 4 * hi) = o;
    }
    if (hi == 0) {
        PM[prow] = m_run;
        PS[prow] = accs[0];
    }
}

// ---------------------------------------------------------------------------
// Combine the 2 kv-splits: O = (O0*a0 + O1*a1) / (s0*a0 + s1*a1), a=2^(m-mm)
// grid (36 qtiles of 64, 32 bh), block 256
// ---------------------------------------------------------------------------
__global__ __launch_bounds__(256)
void attn_combine_kernel(const float* __restrict__ PO, const float* __restrict__ PM,
                         const float* __restrict__ PS,
                         u16* __restrict__ oat0T, u16* __restrict__ oat1T)
{
    const int bhh = blockIdx.y;
    const int q = blockIdx.x * 64 + (threadIdx.x >> 2);
    const int d0 = (threadIdx.x & 3) * 16;
    const long long row = (long long)bhh * HW_N + q;
    const long long MS = 32LL * HW_N;          // split stride for PM/PS
    const long long POS = MS * 64;             // split stride for PO

    const float m0 = PM[row], m1 = PM[MS + row];
    const float s0 = PS[row], s1 = PS[MS + row];
    const float mm = fmaxf(m0, m1);
    const float a0 = exp2f(m0 - mm), a1 = exp2f(m1 - mm);
    const float inv = 1.0f / (s0 * a0 + s1 * a1);
    const float w0 = a0 * inv, w1 = a1 * inv;

    const float* p0 = PO + row * 64 + d0;
    const float* p1 = p0 + POS;
    const int zz = bhh >> 3, h = bhh & 7;
    const int b = zz >> 1, dir = zz & 1;
    u16* out = (dir ? oat1T : oat0T) + ((long long)(b * 8 + h) * HW_N + q) * 64 + d0;
#pragma unroll
    for (int i = 0; i < 4; ++i) {
        const float4 v0 = *(const float4*)(p0 + 4 * i);
        const float4 v1 = *(const float4*)(p1 + 4 * i);
        ushort4 pk;
        pk.x = bfbits(v0.x * w0 + v1.x * w1);
        pk.y = bfbits(v0.y * w0 + v1.y * w1);
        pk.z = bfbits(v0.z * w0 + v1.z * w1);
        pk.w = bfbits(v0.w * w0 + v1.w * w1);
        *(ushort4*)(out + 4 * i) = pk;
    }
}

// ---------------------------------------------------------------------------
// Channel LayerNorm on transposed layout (unchanged)
// ---------------------------------------------------------------------------
__global__ __launch_bounds__(256)
void ln_t_kernel(const float* __restrict__ mpre0T, const float* __restrict__ mpre1T,
                 const float* __restrict__ g1, const float* __restrict__ b1,
                 const float* __restrict__ g2, const float* __restrict__ b2,
                 u16* __restrict__ mln0T, u16* __restrict__ mln1T)
{
    const int l = blockIdx.x * 64 + (threadIdx.x >> 2);
    const int z = blockIdx.y, dir = blockIdx.z;
    const float* src = (dir ? mpre1T : mpre0T) + ((long long)z * HW_N + l) * 256;
    const float* gg = dir ? g2 : g1;
    const float* bb = dir ? b2 : b1;
    u16* dst = (dir ? mln1T : mln0T) + ((long long)z * HW_N + l) * 256;
    const int q = (threadIdx.x & 3) * 64;

    float4 vbuf[16];
    float sum = 0.f, sq = 0.f;
#pragma unroll
    for (int i = 0; i < 16; ++i) {
        const float4 v = *(const float4*)(src + q + i * 4);
        vbuf[i] = v;
        sum += (v.x + v.y) + (v.z + v.w);
        sq += (v.x * v.x + v.y * v.y) + (v.z * v.z + v.w * v.w);
    }
    sum += __shfl_xor(sum, 1, 64); sum += __shfl_xor(sum, 2, 64);
    sq  += __shfl_xor(sq, 1, 64);  sq  += __shfl_xor(sq, 2, 64);
    const float mean = sum * (1.f / 256.f);
    const float var = sq * (1.f / 256.f) - mean * mean;
    const float rstd = rsqrtf(var + EPS_F);
#pragma unroll
    for (int i = 0; i < 16; ++i) {
        const int c = q + i * 4;
        const float4 gv = *(const float4*)(gg + c);
        const float4 bv = *(const float4*)(bb + c);
        ushort4 pk;
        pk.x = bfbits((vbuf[i].x - mean) * rstd * gv.x + bv.x);
        pk.y = bfbits((vbuf[i].y - mean) * rstd * gv.y + bv.y);
        pk.z = bfbits((vbuf[i].z - mean) * rstd * gv.z + bv.z);
        pk.w = bfbits((vbuf[i].w - mean) * rstd * gv.w + bv.w);
        *(ushort4*)(dst + c) = pk;
    }
}

// ---------------------------------------------------------------------------
extern "C" void kernel_launch(void* const* d_in, const int* in_sizes, int n_in,
                              void* d_out, int out_size, void* d_ws, size_t ws_size,
                              hipStream_t stream)
{
    (void)in_sizes; (void)n_in; (void)out_size; (void)ws_size;

    const float* modal1 = (const float*)d_in[0];
    const float* modal2 = (const float*)d_in[1];
    const float* wqkv[6]; const float* bqkv[6];
    for (int j = 0; j < 6; ++j) {
        wqkv[j] = (const float*)d_in[2 + 2 * j];
        bqkv[j] = (const float*)d_in[3 + 2 * j];
    }
    const float* wo1 = (const float*)d_in[14];
    const float* bo1 = (const float*)d_in[15];
    const float* wo2 = (const float*)d_in[16];
    const float* bo2 = (const float*)d_in[17];
    const float* ln1_g = (const float*)d_in[18];
    const float* ln1_b = (const float*)d_in[19];
    const float* ln2_g = (const float*)d_in[20];
    const float* ln2_b = (const float*)d_in[21];
    const float* wf = (const float*)d_in[22];
    const float* bf = (const float*)d_in[23];
    const float* bn_g = (const float*)d_in[24];
    const float* bn_b = (const float*)d_in[25];
    const float* bn_mean = (const float*)d_in[26];
    const float* bn_var = (const float*)d_in[27];

    char* ws = (char*)d_ws;
    size_t off = 0;
    auto alloc = [&](size_t bytes) { char* p = ws + off; off += (bytes + 255) & ~(size_t)255; return p; };

    u16* modalT[2]; u16* wbf[9]; u16* qT[2]; u16* kT[2]; u16* vC[2];
    u16* oatT[2];
    for (int i = 0; i < 2; ++i) modalT[i] = (u16*)alloc(2LL * HW_N * 256 * 2);
    for (int i = 0; i < 9; ++i) wbf[i] = (u16*)alloc(131072 * 2);
    for (int i = 0; i < 2; ++i) qT[i] = (u16*)alloc(2LL * 512 * HW_N * 2);
    for (int i = 0; i < 2; ++i) kT[i] = (u16*)alloc(2LL * 512 * HW_N * 2);
    for (int i = 0; i < 2; ++i) vC[i] = (u16*)alloc(2LL * 512 * HW_N * 2);
    for (int i = 0; i < 2; ++i) oatT[i] = (u16*)alloc(2LL * 512 * HW_N * 2);

    // region shared by attn partials (first) and mpreT/mlnT (later, disjoint life)
    const size_t PO_BYTES = 2LL * 32 * HW_N * 64 * 4;   // 37.75 MB
    const size_t PMS_BYTES = 2LL * 32 * HW_N * 4;       // 0.59 MB each
    char* region = alloc(PO_BYTES + 2 * PMS_BYTES);
    float* PO = (float*)region;
    float* PM = (float*)(region + PO_BYTES);
    float* PS = (float*)(region + PO_BYTES + PMS_BYTES);
    float* mpreT[2]; u16* mlnT[2];
    mpreT[0] = (float*)region;
    mpreT[1] = (float*)(region + 2LL * HW_N * 256 * 4);
    mlnT[0] = (u16*)(region + 4LL * HW_N * 256 * 4);
    mlnT[1] = (u16*)(region + 4LL * HW_N * 256 * 4 + 2LL * HW_N * 256 * 2);

    WPtrs wp;
    for (int j = 0; j < 6; ++j) { wp.s[j] = wqkv[j]; wp.d[j] = wbf[j]; }
    wp.s[6] = wo1; wp.d[6] = wbf[6];
    wp.s[7] = wo2; wp.d[7] = wbf[7];
    wp.s[8] = wf;  wp.d[8] = wbf[8];
    conv_w_kernel<<<dim3(128, 1, 9), 256, 0, stream>>>(wp);
    prep_modal_kernel<<<dim3(36, 4, 4), 256, 0, stream>>>(modal1, modal2, modalT[0], modalT[1]);

    GArgs g0 = {};
    for (int j = 0; j < 6; ++j) { g0.W[j] = wbf[j]; g0.bias[j] = bqkv[j]; }
    g0.X[0] = modalT[0]; g0.X[1] = modalT[1];
    for (int i = 0; i < 2; ++i) { g0.outQ[i] = qT[i]; g0.outK[i] = kT[i]; g0.outV[i] = vC[i]; }
    gemm_mfma<0><<<dim3(72, 2, 6), 256, 0, stream>>>(g0);

    attn_mfma_kernel<<<dim3(1152), 256, 0, stream>>>(
        qT[0], kT[0], vC[0], qT[1], kT[1], vC[1], PO, PM, PS);
    attn_combine_kernel<<<dim3(36, 32), 256, 0, stream>>>(PO, PM, PS, oatT[0], oatT[1]);

    GArgs g1a = {};
    g1a.W[0] = wbf[6]; g1a.W[1] = wbf[7];
    g1a.bias[0] = bo1; g1a.bias[1] = bo2;
    g1a.X[0] = oatT[0]; g1a.X[1] = oatT[1];
    g1a.R[0] = modalT[0]; g1a.R[1] = modalT[1];
    g1a.outT[0] = mpreT[0]; g1a.outT[1] = mpreT[1];
    gemm_mfma<1><<<dim3(36, 2, 2), 256, 0, stream>>>(g1a);

    ln_t_kernel<<<dim3(36, 2, 2), 256, 0, stream>>>(
        mpreT[0], mpreT[1], ln1_g, ln1_b, ln2_g, ln2_b, mlnT[0], mlnT[1]);

    GArgs g2a = {};
    g2a.W[0] = wbf[8]; g2a.bias[0] = bf;
    g2a.X[0] = mlnT[0]; g2a.X[1] = mlnT[1];
    g2a.outC = (float*)d_out;
    g2a.bnm = bn_mean; g2a.bnv = bn_var; g2a.bng = bn_g; g2a.bnb = bn_b;
    gemm_mfma<2><<<dim3(36, 2, 1), 256, 0, stream>>>(g2a);
}

// Round 8
// 161.366 us; speedup vs baseline: 1.9915x; 1.9915x over previous
//
#include <hip/hip_runtime.h>
#include <hip/hip_bf16.h>

#define HW_N 2304
#define EPS_F 1e-5f
#define QSCALE 0.18033688011112043f   // 0.125 * log2(e)

typedef float f32x4 __attribute__((ext_vector_type(4)));
typedef float f32x16 __attribute__((ext_vector_type(16)));
typedef unsigned u32x4 __attribute__((ext_vector_type(4)));
typedef short short8v __attribute__((ext_vector_type(8)));
typedef __bf16 bf16x8 __attribute__((ext_vector_type(8)));
typedef unsigned short u16;

__device__ __forceinline__ f32x4 mfma_bf16(bf16x8 a, bf16x8 b, f32x4 c) {
    return __builtin_amdgcn_mfma_f32_16x16x32_bf16(a, b, c, 0, 0, 0);
}
__device__ __forceinline__ f32x16 mfma32(bf16x8 a, bf16x8 b, f32x16 c) {
    return __builtin_amdgcn_mfma_f32_32x32x16_bf16(a, b, c, 0, 0, 0);
}
__device__ __forceinline__ bf16x8 ld8(const void* p) {
    return __builtin_bit_cast(bf16x8, *(const short8v*)p);
}
__device__ __forceinline__ unsigned short bfbits(float v) {
    return __builtin_bit_cast(unsigned short, __float2bfloat16(v));
}
__device__ __forceinline__ float b2f(u16 u) {
    unsigned x = (unsigned)u << 16;
    return __builtin_bit_cast(float, x);
}
__device__ __forceinline__ unsigned pack2(float lo, float hi) {
    return (unsigned)bfbits(lo) | ((unsigned)bfbits(hi) << 16);
}
// single-instruction 2^x (softmax domain: x <= 8, large-negative flushes to 0)
__device__ __forceinline__ float exp2_fast(float x) {
    float r;
    asm("v_exp_f32 %0, %1" : "=v"(r) : "v"(x));
    return r;
}
// single-instruction pack of two f32 -> 2xbf16 (lo in low16, hi in high16)
__device__ __forceinline__ unsigned cvt_pk(float lo, float hi) {
    unsigned r;
    asm("v_cvt_pk_bf16_f32 %0, %1, %2" : "=v"(r) : "v"(lo), "v"(hi));
    return r;
}
__device__ __forceinline__ f32x16 zero16() {
    f32x16 z;
#pragma unroll
    for (int i = 0; i < 16; ++i) z[i] = 0.f;
    return z;
}

// ---------------------------------------------------------------------------
// Prep: convert 9 weight matrices fp32 -> bf16
// ---------------------------------------------------------------------------
struct WPtrs { const float* s[9]; u16* d[9]; };

__global__ __launch_bounds__(256)
void conv_w_kernel(WPtrs p)
{
    const int j = blockIdx.z;
    const float* s = p.s[j];
    u16* d = p.d[j];
    const int i = (blockIdx.x * 256 + threadIdx.x) * 4;
    const float4 v = *(const float4*)(s + i);
    ushort4 pk;
    pk.x = bfbits(v.x); pk.y = bfbits(v.y); pk.z = bfbits(v.z); pk.w = bfbits(v.w);
    *(ushort4*)(d + i) = pk;
}

// ---------------------------------------------------------------------------
// Prep: transpose modal feats [b][256][2304] fp32 -> [b][2304][256] bf16
// ---------------------------------------------------------------------------
__global__ __launch_bounds__(256)
void prep_modal_kernel(const float* __restrict__ m1, const float* __restrict__ m2,
                       u16* __restrict__ t1, u16* __restrict__ t2)
{
    const int l0 = blockIdx.x * 64, c0 = blockIdx.y * 64;
    const int which = blockIdx.z >> 1, b = blockIdx.z & 1;
    const float* src = (which ? m2 : m1) + ((long long)b * 256 + c0) * HW_N + l0;
    u16* dst = (which ? t2 : t1) + ((long long)b * HW_N + l0) * 256 + c0;

    __shared__ float tile[64][65];
    const int t = threadIdx.x;
    const int r = t >> 4, cq = (t & 15) * 4;
#pragma unroll
    for (int i = 0; i < 4; ++i) {
        const int row = r + i * 16;
        const float4 v = *(const float4*)(src + (long long)row * HW_N + cq);
        tile[row][cq + 0] = v.x; tile[row][cq + 1] = v.y;
        tile[row][cq + 2] = v.z; tile[row][cq + 3] = v.w;
    }
    __syncthreads();
#pragma unroll
    for (int i = 0; i < 4; ++i) {
        const int lr = r + i * 16;
        ushort4 pk;
        pk.x = bfbits(tile[cq + 0][lr]);
        pk.y = bfbits(tile[cq + 1][lr]);
        pk.z = bfbits(tile[cq + 2][lr]);
        pk.w = bfbits(tile[cq + 3][lr]);
        *(ushort4*)(dst + (long long)lr * 256 + cq) = pk;
    }
}

// ---------------------------------------------------------------------------
// Generic MFMA GEMM (unchanged)
// ---------------------------------------------------------------------------
struct GArgs {
    const u16* W[6];
    const float* bias[6];
    const u16* X[2];
    const u16* R[2];
    u16* outQ[2]; u16* outK[2]; u16* outV[2];
    float* outT[2];
    float* outC;
    const float *bnm, *bnv, *bng, *bnb;
};

template<int MODE>
__global__ __launch_bounds__(256)
void gemm_mfma(GArgs g)
{
    constexpr int KD = (MODE == 0) ? 256 : 512;
    constexpr int NS = KD / 32;
    const int z = blockIdx.y;
    const int j = blockIdx.z;
    const int mt_b = blockIdx.x / 18;
    const int nt_b = blockIdx.x - mt_b * 18;
    const int m0 = mt_b * 128, n0 = nt_b * 128;

    const u16* Wb = g.W[(MODE == 2) ? 0 : j];
    const u16* Xb0 = (MODE == 0) ? g.X[(j < 3) ? 0 : 1]
                                 : ((MODE == 1) ? g.X[j] : nullptr);

    __shared__ u16 Als[4096];
    __shared__ u16 Bls[4096];

    const int tid = threadIdx.x;
    const int w = tid >> 6, lane = tid & 63;
    const int l16 = lane & 15, lg = lane >> 4;

    const int ar0 = (((tid >> 6) << 4) | (tid & 15));
    const int k8 = (tid >> 4) & 3;

    short8v sa0, sa1, sb0, sb1;

    auto stage = [&](int kb) {
        const int koff = kb + k8 * 8;
        sa0 = *(const short8v*)(Wb + (long long)(m0 + ar0) * KD + koff);
        sa1 = *(const short8v*)(Wb + (long long)(m0 + ar0 + 64) * KD + koff);
        if constexpr (MODE == 0) {
            const u16* p = Xb0 + ((long long)z * HW_N + n0 + ar0) * 256 + koff;
            sb0 = *(const short8v*)p;
            sb1 = *(const short8v*)(p + 64LL * 256);
        } else if constexpr (MODE == 1) {
            const int head = kb >> 6;
            const u16* p = Xb0 + (((long long)z * 8 + head) * HW_N + n0 + ar0) * 64 + (koff & 63);
            sb0 = *(const short8v*)p;
            sb1 = *(const short8v*)(p + 64LL * 64);
        } else {
            const u16* Xb = (kb < 256) ? g.X[0] : g.X[1];
            const u16* p = Xb + ((long long)z * HW_N + n0 + ar0) * 256 + (koff & 255);
            sb0 = *(const short8v*)p;
            sb1 = *(const short8v*)(p + 64LL * 256);
        }
    };

    f32x4 acc[4][4];
#pragma unroll
    for (int a = 0; a < 4; ++a)
#pragma unroll
        for (int b = 0; b < 4; ++b) acc[a][b] = f32x4{0.f, 0.f, 0.f, 0.f};

    stage(0);
    for (int s = 0; s < NS; ++s) {
        __syncthreads();
        *(short8v*)((char*)Als + tid * 16) = sa0;
        *(short8v*)((char*)Als + tid * 16 + 4096) = sa1;
        *(short8v*)((char*)Bls + tid * 16) = sb0;
        *(short8v*)((char*)Bls + tid * 16 + 4096) = sb1;
        __syncthreads();
        if (s + 1 < NS) stage((s + 1) * 32);

        bf16x8 bfr[4];
#pragma unroll
        for (int nt = 0; nt < 4; ++nt)
            bfr[nt] = ld8((char*)Bls + ((w & 1) * 4 + nt) * 1024 + lane * 16);
#pragma unroll
        for (int mt = 0; mt < 4; ++mt) {
            const bf16x8 af = ld8((char*)Als + ((w >> 1) * 4 + mt) * 1024 + lane * 16);
#pragma unroll
            for (int nt = 0; nt < 4; ++nt)
                acc[mt][nt] = mfma_bf16(af, bfr[nt], acc[mt][nt]);
        }
    }

    const int mbase = m0 + (w >> 1) * 64 + 4 * lg;
    const int nbase = n0 + (w & 1) * 64 + l16;

    if constexpr (MODE == 0) {
        const int kind = j % 3, which = j / 3;
        const float* Bp = g.bias[j];
        if (kind < 2) {
            u16* T = (kind == 0) ? g.outQ[which] : g.outK[which];
            const float s = (kind == 0) ? QSCALE : 1.0f;
#pragma unroll
            for (int mt = 0; mt < 4; ++mt) {
                const int m = mbase + mt * 16;
                const float4 bv = *(const float4*)(Bp + m);
#pragma unroll
                for (int nt = 0; nt < 4; ++nt) {
                    const int l = nbase + nt * 16;
                    const f32x4 a = acc[mt][nt];
                    ushort4 pk;
                    pk.x = bfbits((a.x + bv.x) * s);
                    pk.y = bfbits((a.y + bv.y) * s);
                    pk.z = bfbits((a.z + bv.z) * s);
                    pk.w = bfbits((a.w + bv.w) * s);
                    *(ushort4*)(T + ((long long)(z * 8 + (m >> 6)) * HW_N + l) * 64 + (m & 63)) = pk;
                }
            }
        } else {
            u16* V = g.outV[which];
#pragma unroll
            for (int mt = 0; mt < 4; ++mt) {
                const int m = mbase + mt * 16;
                const float4 bv = *(const float4*)(Bp + m);
#pragma unroll
                for (int nt = 0; nt < 4; ++nt) {
                    const int l = nbase + nt * 16;
                    const f32x4 a = acc[mt][nt];
                    V[((long long)z * 512 + m + 0) * HW_N + l] = bfbits(a.x + bv.x);
                    V[((long long)z * 512 + m + 1) * HW_N + l] = bfbits(a.y + bv.y);
                    V[((long long)z * 512 + m + 2) * HW_N + l] = bfbits(a.z + bv.z);
                    V[((long long)z * 512 + m + 3) * HW_N + l] = bfbits(a.w + bv.w);
                }
            }
        }
    } else if constexpr (MODE == 1) {
        const float* Bp = g.bias[j];
        const u16* Rb = g.R[j];
        float* Ob = g.outT[j];
#pragma unroll
        for (int mt = 0; mt < 4; ++mt) {
            const int m = mbase + mt * 16;
            const float4 bv = *(const float4*)(Bp + m);
#pragma unroll
            for (int nt = 0; nt < 4; ++nt) {
                const int l = nbase + nt * 16;
                const long long rowoff = ((long long)z * HW_N + l) * 256 + m;
                const ushort4 rv = *(const ushort4*)(Rb + rowoff);
                const f32x4 a = acc[mt][nt];
                float4 o;
                o.x = a.x + bv.x + b2f(rv.x);
                o.y = a.y + bv.y + b2f(rv.y);
                o.z = a.z + bv.z + b2f(rv.z);
                o.w = a.w + bv.w + b2f(rv.w);
                *(float4*)(Ob + rowoff) = o;
            }
        }
    } else {
        const float* Bp = g.bias[0];
#pragma unroll
        for (int mt = 0; mt < 4; ++mt) {
            const int m = mbase + mt * 16;
            const float4 bv = *(const float4*)(Bp + m);
            const float4 mu = *(const float4*)(g.bnm + m);
            const float4 vr = *(const float4*)(g.bnv + m);
            const float4 ga = *(const float4*)(g.bng + m);
            const float4 be = *(const float4*)(g.bnb + m);
            const float sc0 = ga.x * rsqrtf(vr.x + EPS_F), sh0 = be.x - mu.x * sc0;
            const float sc1 = ga.y * rsqrtf(vr.y + EPS_F), sh1 = be.y - mu.y * sc1;
            const float sc2 = ga.z * rsqrtf(vr.z + EPS_F), sh2 = be.z - mu.z * sc2;
            const float sc3 = ga.w * rsqrtf(vr.w + EPS_F), sh3 = be.w - mu.w * sc3;
#pragma unroll
            for (int nt = 0; nt < 4; ++nt) {
                const int l = nbase + nt * 16;
                const f32x4 a = acc[mt][nt];
                float* O = g.outC + (long long)z * 256 * HW_N + l;
                O[(long long)(m + 0) * HW_N] = fmaxf((a.x + bv.x) * sc0 + sh0, 0.f);
                O[(long long)(m + 1) * HW_N] = fmaxf((a.y + bv.y) * sc1 + sh1, 0.f);
                O[(long long)(m + 2) * HW_N] = fmaxf((a.z + bv.z) * sc2 + sh2, 0.f);
                O[(long long)(m + 3) * HW_N] = fmaxf((a.w + bv.w) * sc3 + sh3, 0.f);
            }
        }
    }
}

// ---------------------------------------------------------------------------
// MFMA flash cross-attention v6 (= v4 structure + fast VALU):
//   - exp2 via raw v_exp_f32 (1 trans op vs OCML sequence)
//   - P pack via v_cvt_pk_bf16_f32 (1 op per f32 pair)
//   - conflict-free row^(row>>3) swizzle, dbuf LDS, hoisted frags, in-reg P,
//     ones-MFMA denominator, defer-max
// ---------------------------------------------------------------------------
__global__ __launch_bounds__(256)
void attn_mfma_kernel(const u16* __restrict__ qt0, const u16* __restrict__ kt0,
                      const u16* __restrict__ v0b,
                      const u16* __restrict__ qt1, const u16* __restrict__ kt1,
                      const u16* __restrict__ v1b,
                      u16* __restrict__ oat0T, u16* __restrict__ oat1T)
{
    const int flat = blockIdx.x;
    const int virt = (flat & 7) * 72 + (flat >> 3);
    const int lt = virt % 18;
    const int hz = virt / 18;
    const int h = hz & 7;
    const int zz = hz >> 3;
    const int b = zz >> 1, dir = zz & 1;

    const u16* QT = dir ? qt1 : qt0;
    const u16* KT = dir ? kt0 : kt1;
    const u16* V  = dir ? v0b : v1b;

    const long long bh = (long long)(b * 8 + h);
    const u16* Qb = QT + bh * HW_N * 64;
    const u16* Kb = KT + bh * HW_N * 64;
    const u16* Vb = V + ((long long)b * 512 + h * 64) * HW_N;

    const int tid = threadIdx.x;
    const int w = tid >> 6, lane = tid & 63;
    const int l32 = lane & 31, hi = lane >> 5;
    const int q0 = lt * 128 + w * 32;

    __shared__ u16 Ks[2][64 * 64];
    __shared__ u16 Vs[2][64 * 64];

    bf16x8 qf0, qf1, qf2, qf3;
    {
        const u16* qrow = Qb + (long long)(q0 + l32) * 64 + 8 * hi;
        qf0 = ld8(qrow);       qf1 = ld8(qrow + 16);
        qf2 = ld8(qrow + 32);  qf3 = ld8(qrow + 48);
    }
    bf16x8 onesv;
    {
        short8v o;
#pragma unroll
        for (int i = 0; i < 8; ++i) o[i] = (short)0x3F80;
        onesv = __builtin_bit_cast(bf16x8, o);
    }

    f32x16 accA = zero16(), accB = zero16(), accs = zero16();
    float m_run = -1e30f;

    auto SWZ = [](int r) { return ((r ^ (r >> 3)) & 7) << 4; };

    // staging (write side)
    const int rsub = lane >> 3;
    const int csub = (lane & 7) * 8;
    const int r0 = 16 * w + rsub, r1 = r0 + 8;
    const int swz0 = (csub * 2) ^ SWZ(r0);
    const int swz1 = (csub * 2) ^ SWZ(r1);

    short8v ka, kb2, va, vb2;
    auto stage = [&](int t) {
        const int m0 = t * 64;
        const u16* kbase = Kb + (long long)(m0 + 16 * w) * 64;
        ka  = *(const short8v*)(kbase + (long long)rsub * 64 + csub);
        kb2 = *(const short8v*)(kbase + (long long)(8 + rsub) * 64 + csub);
        const u16* vbase = Vb + (long long)(16 * w + rsub) * HW_N + m0 + csub;
        va  = *(const short8v*)(vbase);
        vb2 = *(const short8v*)(vbase + 8LL * HW_N);
    };
    auto commit = [&](int buf) {
        *(short8v*)((char*)Ks[buf] + r0 * 128 + swz0) = ka;
        *(short8v*)((char*)Ks[buf] + r1 * 128 + swz1) = kb2;
        *(short8v*)((char*)Vs[buf] + r0 * 128 + swz0) = va;
        *(short8v*)((char*)Vs[buf] + r1 * 128 + swz1) = vb2;
    };

    // fragment-read addressing (rows l32 and l32+32)
    const int rb0 = l32 * 128;
    const int rb1 = (l32 + 32) * 128;
    const int cs0 = (16 * hi) ^ SWZ(l32);
    const int cs1 = (16 * hi) ^ SWZ(l32 + 32);

    stage(0); commit(0); stage(1);
    __syncthreads();

    for (int t = 0; t < 36; ++t) {
        const int cur = t & 1;
        const char* kbase = (const char*)Ks[cur];
        const char* vbase = (const char*)Vs[cur];

        // ---- hoisted K fragment reads (before commit's ds_writes)
        const bf16x8 kf00 = ld8(kbase + rb0 + (cs0 ^ 0));
        const bf16x8 kf01 = ld8(kbase + rb1 + (cs1 ^ 0));
        const bf16x8 kf10 = ld8(kbase + rb0 + (cs0 ^ 32));
        const bf16x8 kf11 = ld8(kbase + rb1 + (cs1 ^ 32));
        const bf16x8 kf20 = ld8(kbase + rb0 + (cs0 ^ 64));
        const bf16x8 kf21 = ld8(kbase + rb1 + (cs1 ^ 64));
        const bf16x8 kf30 = ld8(kbase + rb0 + (cs0 ^ 96));
        const bf16x8 kf31 = ld8(kbase + rb1 + (cs1 ^ 96));

        if (t + 1 < 36) commit(cur ^ 1);
        if (t + 2 < 36) stage(t + 2);

        // ---- QK^T
        f32x16 s0 = zero16(), s1 = zero16();
        __builtin_amdgcn_s_setprio(1);
        s0 = mfma32(kf00, qf0, s0); s1 = mfma32(kf01, qf0, s1);
        s0 = mfma32(kf10, qf1, s0); s1 = mfma32(kf11, qf1, s1);
        s0 = mfma32(kf20, qf2, s0); s1 = mfma32(kf21, qf2, s1);
        s0 = mfma32(kf30, qf3, s0); s1 = mfma32(kf31, qf3, s1);
        __builtin_amdgcn_s_setprio(0);

        // ---- hoisted V fragment reads (latency covered by softmax VALU)
        const bf16x8 vf00 = ld8(vbase + rb0 + (cs0 ^ 0));
        const bf16x8 vf01 = ld8(vbase + rb1 + (cs1 ^ 0));
        const bf16x8 vf10 = ld8(vbase + rb0 + (cs0 ^ 32));
        const bf16x8 vf11 = ld8(vbase + rb1 + (cs1 ^ 32));
        const bf16x8 vf20 = ld8(vbase + rb0 + (cs0 ^ 64));
        const bf16x8 vf21 = ld8(vbase + rb1 + (cs1 ^ 64));
        const bf16x8 vf30 = ld8(vbase + rb0 + (cs0 ^ 96));
        const bf16x8 vf31 = ld8(vbase + rb1 + (cs1 ^ 96));

        // ---- online softmax (log2 domain), defer-max THR=8, max3-friendly tree
        f32x16 mv;
#pragma unroll
        for (int i = 0; i < 16; ++i) mv[i] = fmaxf(s0[i], s1[i]);
        float t0m = fmaxf(fmaxf(mv[0], mv[1]), mv[2]);
        float t1m = fmaxf(fmaxf(mv[3], mv[4]), mv[5]);
        float t2m = fmaxf(fmaxf(mv[6], mv[7]), mv[8]);
        float t3m = fmaxf(fmaxf(mv[9], mv[10]), mv[11]);
        float t4m = fmaxf(fmaxf(mv[12], mv[13]), mv[14]);
        float mx = fmaxf(fmaxf(fmaxf(t0m, t1m), fmaxf(t2m, t3m)), fmaxf(t4m, mv[15]));
        {
            unsigned mu = __builtin_bit_cast(unsigned, mx);
            unsigned mv2 = mu;
            asm("v_permlane32_swap_b32 %0, %1" : "+v"(mu), "+v"(mv2));
            mx = fmaxf(__builtin_bit_cast(float, mu), __builtin_bit_cast(float, mv2));
        }

        if (!__all(mx <= m_run + 8.f)) {
            const float m_new = fmaxf(m_run, mx);
            const float alpha = exp2_fast(m_run - m_new);
#pragma unroll
            for (int i = 0; i < 16; ++i) {
                accA[i] *= alpha; accB[i] *= alpha; accs[i] *= alpha;
            }
            m_run = m_new;
        }

#pragma unroll
        for (int i = 0; i < 16; ++i) {
            s0[i] = exp2_fast(s0[i] - m_run);
            s1[i] = exp2_fast(s1[i] - m_run);
        }

        // ---- pack P (cvt_pk) + permlane32_swap -> PV B-frags; PV + ones denom
        __builtin_amdgcn_s_setprio(1);
#define PVSTEP(S, PT, VF0, VF1) { \
        constexpr int qe = 2 * ((S) & 1), qo = qe + 1; \
        unsigned a0 = cvt_pk(PT[4 * qe + 0], PT[4 * qe + 1]); \
        unsigned b0 = cvt_pk(PT[4 * qe + 2], PT[4 * qe + 3]); \
        unsigned a1 = cvt_pk(PT[4 * qo + 0], PT[4 * qo + 1]); \
        unsigned b1 = cvt_pk(PT[4 * qo + 2], PT[4 * qo + 3]); \
        asm("v_permlane32_swap_b32 %0, %1" : "+v"(a0), "+v"(a1)); \
        asm("v_permlane32_swap_b32 %0, %1" : "+v"(b0), "+v"(b1)); \
        u32x4 pw = {a0, b0, a1, b1}; \
        const bf16x8 pf = __builtin_bit_cast(bf16x8, pw); \
        accA = mfma32(VF0, pf, accA); \
        accB = mfma32(VF1, pf, accB); \
        accs = mfma32(onesv, pf, accs); }
        PVSTEP(0, s0, vf00, vf01)
        PVSTEP(1, s0, vf10, vf11)
        PVSTEP(2, s1, vf20, vf21)
        PVSTEP(3, s1, vf30, vf31)
#undef PVSTEP
        __builtin_amdgcn_s_setprio(0);

        __syncthreads();
    }

    const float inv = 1.0f / accs[0];
    u16* obase = (dir ? oat1T : oat0T) + (bh * HW_N + q0 + l32) * 64;
#pragma unroll
    for (int g = 0; g < 4; ++g) {
        ushort4 pk;
        pk.x = bfbits(accA[4 * g + 0] * inv);
        pk.y = bfbits(accA[4 * g + 1] * inv);
        pk.z = bfbits(accA[4 * g + 2] * inv);
        pk.w = bfbits(accA[4 * g + 3] * inv);
        *(ushort4*)(obase + 8 * g + 4 * hi) = pk;
        pk.x = bfbits(accB[4 * g + 0] * inv);
        pk.y = bfbits(accB[4 * g + 1] * inv);
        pk.z = bfbits(accB[4 * g + 2] * inv);
        pk.w = bfbits(accB[4 * g + 3] * inv);
        *(ushort4*)(obase + 32 + 8 * g + 4 * hi) = pk;
    }
}

// ---------------------------------------------------------------------------
// Channel LayerNorm on transposed layout (unchanged)
// ---------------------------------------------------------------------------
__global__ __launch_bounds__(256)
void ln_t_kernel(const float* __restrict__ mpre0T, const float* __restrict__ mpre1T,
                 const float* __restrict__ g1, const float* __restrict__ b1,
                 const float* __restrict__ g2, const float* __restrict__ b2,
                 u16* __restrict__ mln0T, u16* __restrict__ mln1T)
{
    const int l = blockIdx.x * 64 + (threadIdx.x >> 2);
    const int z = blockIdx.y, dir = blockIdx.z;
    const float* src = (dir ? mpre1T : mpre0T) + ((long long)z * HW_N + l) * 256;
    const float* gg = dir ? g2 : g1;
    const float* bb = dir ? b2 : b1;
    u16* dst = (dir ? mln1T : mln0T) + ((long long)z * HW_N + l) * 256;
    const int q = (threadIdx.x & 3) * 64;

    float4 vbuf[16];
    float sum = 0.f, sq = 0.f;
#pragma unroll
    for (int i = 0; i < 16; ++i) {
        const float4 v = *(const float4*)(src + q + i * 4);
        vbuf[i] = v;
        sum += (v.x + v.y) + (v.z + v.w);
        sq += (v.x * v.x + v.y * v.y) + (v.z * v.z + v.w * v.w);
    }
    sum += __shfl_xor(sum, 1, 64); sum += __shfl_xor(sum, 2, 64);
    sq  += __shfl_xor(sq, 1, 64);  sq  += __shfl_xor(sq, 2, 64);
    const float mean = sum * (1.f / 256.f);
    const float var = sq * (1.f / 256.f) - mean * mean;
    const float rstd = rsqrtf(var + EPS_F);
#pragma unroll
    for (int i = 0; i < 16; ++i) {
        const int c = q + i * 4;
        const float4 gv = *(const float4*)(gg + c);
        const float4 bv = *(const float4*)(bb + c);
        ushort4 pk;
        pk.x = bfbits((vbuf[i].x - mean) * rstd * gv.x + bv.x);
        pk.y = bfbits((vbuf[i].y - mean) * rstd * gv.y + bv.y);
        pk.z = bfbits((vbuf[i].z - mean) * rstd * gv.z + bv.z);
        pk.w = bfbits((vbuf[i].w - mean) * rstd * gv.w + bv.w);
        *(ushort4*)(dst + c) = pk;
    }
}

// ---------------------------------------------------------------------------
extern "C" void kernel_launch(void* const* d_in, const int* in_sizes, int n_in,
                              void* d_out, int out_size, void* d_ws, size_t ws_size,
                              hipStream_t stream)
{
    (void)in_sizes; (void)n_in; (void)out_size; (void)ws_size;

    const float* modal1 = (const float*)d_in[0];
    const float* modal2 = (const float*)d_in[1];
    const float* wqkv[6]; const float* bqkv[6];
    for (int j = 0; j < 6; ++j) {
        wqkv[j] = (const float*)d_in[2 + 2 * j];
        bqkv[j] = (const float*)d_in[3 + 2 * j];
    }
    const float* wo1 = (const float*)d_in[14];
    const float* bo1 = (const float*)d_in[15];
    const float* wo2 = (const float*)d_in[16];
    const float* bo2 = (const float*)d_in[17];
    const float* ln1_g = (const float*)d_in[18];
    const float* ln1_b = (const float*)d_in[19];
    const float* ln2_g = (const float*)d_in[20];
    const float* ln2_b = (const float*)d_in[21];
    const float* wf = (const float*)d_in[22];
    const float* bf = (const float*)d_in[23];
    const float* bn_g = (const float*)d_in[24];
    const float* bn_b = (const float*)d_in[25];
    const float* bn_mean = (const float*)d_in[26];
    const float* bn_var = (const float*)d_in[27];

    char* ws = (char*)d_ws;
    size_t off = 0;
    auto alloc = [&](size_t bytes) { char* p = ws + off; off += (bytes + 255) & ~(size_t)255; return p; };

    u16* modalT[2]; u16* wbf[9]; u16* qT[2]; u16* kT[2]; u16* vC[2];
    u16* oatT[2]; float* mpreT[2]; u16* mlnT[2];
    for (int i = 0; i < 2; ++i) modalT[i] = (u16*)alloc(2LL * HW_N * 256 * 2);
    for (int i = 0; i < 9; ++i) wbf[i] = (u16*)alloc(131072 * 2);
    for (int i = 0; i < 2; ++i) qT[i] = (u16*)alloc(2LL * 512 * HW_N * 2);
    for (int i = 0; i < 2; ++i) kT[i] = (u16*)alloc(2LL * 512 * HW_N * 2);
    for (int i = 0; i < 2; ++i) vC[i] = (u16*)alloc(2LL * 512 * HW_N * 2);
    for (int i = 0; i < 2; ++i) oatT[i] = (u16*)alloc(2LL * 512 * HW_N * 2);
    for (int i = 0; i < 2; ++i) mpreT[i] = (float*)alloc(2LL * HW_N * 256 * 4);
    for (int i = 0; i < 2; ++i) mlnT[i] = (u16*)alloc(2LL * HW_N * 256 * 2);

    WPtrs wp;
    for (int j = 0; j < 6; ++j) { wp.s[j] = wqkv[j]; wp.d[j] = wbf[j]; }
    wp.s[6] = wo1; wp.d[6] = wbf[6];
    wp.s[7] = wo2; wp.d[7] = wbf[7];
    wp.s[8] = wf;  wp.d[8] = wbf[8];
    conv_w_kernel<<<dim3(128, 1, 9), 256, 0, stream>>>(wp);
    prep_modal_kernel<<<dim3(36, 4, 4), 256, 0, stream>>>(modal1, modal2, modalT[0], modalT[1]);

    GArgs g0 = {};
    for (int j = 0; j < 6; ++j) { g0.W[j] = wbf[j]; g0.bias[j] = bqkv[j]; }
    g0.X[0] = modalT[0]; g0.X[1] = modalT[1];
    for (int i = 0; i < 2; ++i) { g0.outQ[i] = qT[i]; g0.outK[i] = kT[i]; g0.outV[i] = vC[i]; }
    gemm_mfma<0><<<dim3(72, 2, 6), 256, 0, stream>>>(g0);

    attn_mfma_kernel<<<dim3(576), 256, 0, stream>>>(
        qT[0], kT[0], vC[0], qT[1], kT[1], vC[1], oatT[0], oatT[1]);

    GArgs g1a = {};
    g1a.W[0] = wbf[6]; g1a.W[1] = wbf[7];
    g1a.bias[0] = bo1; g1a.bias[1] = bo2;
    g1a.X[0] = oatT[0]; g1a.X[1] = oatT[1];
    g1a.R[0] = modalT[0]; g1a.R[1] = modalT[1];
    g1a.outT[0] = mpreT[0]; g1a.outT[1] = mpreT[1];
    gemm_mfma<1><<<dim3(36, 2, 2), 256, 0, stream>>>(g1a);

    ln_t_kernel<<<dim3(36, 2, 2), 256, 0, stream>>>(
        mpreT[0], mpreT[1], ln1_g, ln1_b, ln2_g, ln2_b, mlnT[0], mlnT[1]);

    GArgs g2a = {};
    g2a.W[0] = wbf[8]; g2a.bias[0] = bf;
    g2a.X[0] = mlnT[0]; g2a.X[1] = mlnT[1];
    g2a.outC = (float*)d_out;
    g2a.bnm = bn_mean; g2a.bnv = bn_var; g2a.bng = bn_g; g2a.bnb = bn_b;
    gemm_mfma<2><<<dim3(36, 2, 1), 256, 0, stream>>>(g2a);
}